// Round 1
// baseline (6434.657 us; speedup 1.0000x reference)
//
#include <hip/hip_runtime.h>
#include <stdint.h>

#define NB 256          // batch
#define NH 1024         // hidden
#define NPOSE 135
#define NPPAD 160       // pose padded to 160 (mult of 32)
#define NSTEPS 143      // 119 encoder + 24 decoder cell steps
#define NDEC 24
#define KTOT 1184       // 1024 (h) + 160 (x padded)
#define LSTR 168        // LDS row stride in elems (pad breaks bank pattern)
#define NWG 256

typedef __bf16 bf16;
typedef __attribute__((ext_vector_type(8))) __bf16 bf16x8;
typedef __attribute__((ext_vector_type(4))) float f32x4;

// ---- ws layout (bytes), all 256-aligned ----
#define WCAT_OFF 0
#define WCAT_BYTES (4096l * KTOT * 2)              // 9,699,328
#define WFC_OFF  (WCAT_OFF + WCAT_BYTES)
#define WFC_BYTES (144l * 1024 * 2)                // 294,912
#define X_OFF    (WFC_OFF + WFC_BYTES)
#define X_BYTES  (143l * NB * NPPAD * 2)           // 11,714,560
#define H_OFF    (X_OFF + X_BYTES)
#define H_BYTES  (2l * NB * NH * 2)                // ping-pong h, 1,048,576
#define BAR_OFF  (H_OFF + H_BYTES)
#define BAR_BYTES (1024 * 4)

__global__ void k_zero(uint32_t* p, int n) {
  int i = blockIdx.x * blockDim.x + threadIdx.x;
  int st = gridDim.x * blockDim.x;
  for (; i < n; i += st) p[i] = 0u;
}

// W_cat[n][k] bf16: k<1024 -> W_hh[n][k]; 1024<=k<1159 -> W_ih[n][k-1024]; else 0
__global__ void k_wcat(const float* __restrict__ Whh, const float* __restrict__ Wih,
                       bf16* __restrict__ W) {
  int n = blockIdx.x;
  for (int kk = threadIdx.x; kk < KTOT; kk += blockDim.x) {
    float v = 0.f;
    if (kk < NH) v = Whh[(size_t)n * NH + kk];
    else if (kk - NH < NPOSE) v = Wih[(size_t)n * NPOSE + (kk - NH)];
    W[(size_t)n * KTOT + kk] = (bf16)v;
  }
}

// Wfcb[p][k] bf16, p padded to 144 rows (zeros)
__global__ void k_wfc(const float* __restrict__ Wfc, bf16* __restrict__ W) {
  int p = blockIdx.x;
  for (int kk = threadIdx.x; kk < NH; kk += blockDim.x) {
    float v = (p < NPOSE) ? Wfc[(size_t)p * NH + kk] : 0.f;
    W[(size_t)p * NH + kk] = (bf16)v;
  }
}

// X[t][b][p] bf16 for t=0..119 (encoder inputs + inp0), pad p>=135 with 0
__global__ void k_x(const float* __restrict__ poses, bf16* __restrict__ X) {
  int idx = blockIdx.x;          // t*256 + b, t in [0,120)
  int t = idx >> 8, b = idx & 255;
  int p = threadIdx.x;
  if (p < NPPAD) {
    float v = (p < NPOSE) ? poses[((size_t)b * 144 + t) * NPOSE + p] : 0.f;
    X[(size_t)idx * NPPAD + p] = (bf16)v;
  }
}

__device__ __forceinline__ float sigm(float x) { return 1.f / (1.f + __expf(-x)); }
__device__ __forceinline__ float tanh_(float x) {
  float e = __expf(2.f * x);
  return 1.f - 2.f / (e + 1.f);   // stable for |x| large (inf arithmetic ok)
}

// grid barrier: one slot per sync, slots zeroed each launch (replay-safe)
__device__ __forceinline__ void gbar(int* bar, int slot) {
  __syncthreads();
  if (threadIdx.x == 0) {
    __threadfence();                       // release h/x writes to LLC (cross-XCD)
    atomicAdd(&bar[slot], 1);
    while (__hip_atomic_load(&bar[slot], __ATOMIC_RELAXED, __HIP_MEMORY_SCOPE_AGENT) < NWG)
      __builtin_amdgcn_s_sleep(1);
    __threadfence();                       // acquire: invalidate stale L1/L2
  }
  __syncthreads();
}

__global__ __launch_bounds__(256) void
k_main(const float* __restrict__ poses, const float* __restrict__ bfc,
       const bf16* __restrict__ Wcat, const bf16* __restrict__ Wfcb,
       bf16* __restrict__ X, bf16* __restrict__ H, int* __restrict__ bar,
       float* __restrict__ out) {
  __shared__ bf16 Alds[64 * LSTR];
  __shared__ bf16 Blds[64 * LSTR];
  const int tid  = threadIdx.x;
  const int lane = tid & 63;
  const int wv   = tid >> 6;        // wave 0..3 -> 16-row b slice
  const int cl   = lane & 15;       // frag row (A/B) and output col (C)
  const int quad = lane >> 4;       // k-subblock / output row group
  const int L    = blockIdx.x;
  // XCD-aware mapping: each XCD owns 8 consecutive j-blocks (W L2 residency)
  const int jb = (L & 7) * 8 + ((L >> 3) & 7);   // 0..63
  const int bb = L >> 6;                          // 0..3
  const int b0 = bb * 64;
  const int j0 = jb * 16;

  float cst[4] = {0.f, 0.f, 0.f, 0.f};  // c-state lives in registers all 143 steps
  int slot = 0;

  for (int s = 0; s < NSTEPS; ++s) {
    bf16* Hr = H + (size_t)(s & 1) * (NB * NH);        // read h(s)
    bf16* Hw = H + (size_t)((s + 1) & 1) * (NB * NH);  // write h(s+1)
    f32x4 acc0 = {0,0,0,0}, acc1 = {0,0,0,0}, acc2 = {0,0,0,0}, acc3 = {0,0,0,0};

    for (int ch = 0; ch < 9; ++ch) {
      // ---- stage A (64b x w) and B (64cols x w) into LDS ----
      if (ch < 8) {   // w = 128, from Hr
        const bf16* ga = Hr + (size_t)b0 * NH + ch * 128;
        for (int u = tid; u < 64 * 16; u += 256) {
          int r = u >> 4, iu = u & 15;
          *(bf16x8*)&Alds[r * LSTR + iu * 8] = *(const bf16x8*)&ga[(size_t)r * NH + iu * 8];
        }
        for (int u = tid; u < 64 * 16; u += 256) {
          int r = u >> 4, iu = u & 15;
          int n = (r >> 4) * NH + j0 + (r & 15);       // gate-major col -> W row
          *(bf16x8*)&Blds[r * LSTR + iu * 8] =
              *(const bf16x8*)&Wcat[(size_t)n * KTOT + ch * 128 + iu * 8];
        }
      } else {        // w = 160, from X[s]
        const bf16* ga = X + ((size_t)s * NB + b0) * NPPAD;
        for (int u = tid; u < 64 * 20; u += 256) {
          int r = u / 20, iu = u % 20;
          *(bf16x8*)&Alds[r * LSTR + iu * 8] = *(const bf16x8*)&ga[(size_t)r * NPPAD + iu * 8];
        }
        for (int u = tid; u < 64 * 20; u += 256) {
          int r = u / 20, iu = u % 20;
          int n = (r >> 4) * NH + j0 + (r & 15);
          *(bf16x8*)&Blds[r * LSTR + iu * 8] =
              *(const bf16x8*)&Wcat[(size_t)n * KTOT + NH + iu * 8];
        }
      }
      __syncthreads();
      const int nks = (ch < 8) ? 4 : 5;
      for (int ks = 0; ks < nks; ++ks) {
        bf16x8 af  = *(const bf16x8*)&Alds[(wv * 16 + cl) * LSTR + ks * 32 + quad * 8];
        bf16x8 bf0 = *(const bf16x8*)&Blds[( 0 + cl) * LSTR + ks * 32 + quad * 8];
        bf16x8 bf1 = *(const bf16x8*)&Blds[(16 + cl) * LSTR + ks * 32 + quad * 8];
        bf16x8 bf2 = *(const bf16x8*)&Blds[(32 + cl) * LSTR + ks * 32 + quad * 8];
        bf16x8 bf3 = *(const bf16x8*)&Blds[(48 + cl) * LSTR + ks * 32 + quad * 8];
        acc0 = __builtin_amdgcn_mfma_f32_16x16x32_bf16(af, bf0, acc0, 0, 0, 0);
        acc1 = __builtin_amdgcn_mfma_f32_16x16x32_bf16(af, bf1, acc1, 0, 0, 0);
        acc2 = __builtin_amdgcn_mfma_f32_16x16x32_bf16(af, bf2, acc2, 0, 0, 0);
        acc3 = __builtin_amdgcn_mfma_f32_16x16x32_bf16(af, bf3, acc3, 0, 0, 0);
      }
      __syncthreads();
    }

    // ---- activations + state update; each lane owns (b, j) for r=0..3 ----
    #pragma unroll
    for (int r = 0; r < 4; ++r) {
      float gi = sigm(acc0[r]);
      float gf = sigm(acc1[r]);
      float gg = tanh_(acc2[r]);
      float go = sigm(acc3[r]);
      float cn = gf * cst[r] + gi * gg;
      cst[r] = cn;
      float h = go * tanh_(cn);
      Hw[(size_t)(b0 + wv * 16 + quad * 4 + r) * NH + j0 + cl] = (bf16)h;
    }
    gbar(bar, slot++);

    if (s >= 119) {   // decoder: out = inp + h_new @ W_fc^T + b_fc
      const int k = s - 119;
      if (L < 16) {   // WG L handles batch rows 16L..16L+15
        f32x4 oa[3] = {{0,0,0,0},{0,0,0,0},{0,0,0,0}};
        const bf16* hrow = Hw + (size_t)(L * 16 + cl) * NH;
        for (int ks = 0; ks < 32; ++ks) {
          bf16x8 af = *(const bf16x8*)&hrow[ks * 32 + quad * 8];
          #pragma unroll
          for (int i = 0; i < 3; ++i) {
            int ct = wv + i * 4;           // wave wv covers col-tiles wv, wv+4, wv+8
            if (ct > 8) continue;
            bf16x8 bw = *(const bf16x8*)&Wfcb[(size_t)(ct * 16 + cl) * NH + ks * 32 + quad * 8];
            oa[i] = __builtin_amdgcn_mfma_f32_16x16x32_bf16(af, bw, oa[i], 0, 0, 0);
          }
        }
        #pragma unroll
        for (int i = 0; i < 3; ++i) {
          int ct = wv + i * 4;
          if (ct > 8) continue;
          int p = ct * 16 + cl;
          if (p < NPOSE) {
            #pragma unroll
            for (int r = 0; r < 4; ++r) {
              int b = L * 16 + quad * 4 + r;
              float inp = (k == 0) ? poses[((size_t)b * 144 + 119) * NPOSE + p]
                                   : out[((size_t)b * NDEC + (k - 1)) * NPOSE + p];
              float v = oa[i][r] + inp + bfc[p];     // additive chain kept fp32
              out[((size_t)b * NDEC + k) * NPOSE + p] = v;
              if (s + 1 < NSTEPS)
                X[((size_t)(s + 1) * NB + b) * NPPAD + p] = (bf16)v;
            }
          }
        }
      }
      gbar(bar, slot++);
    }
  }
}

extern "C" void kernel_launch(void* const* d_in, const int* in_sizes, int n_in,
                              void* d_out, int out_size, void* d_ws, size_t ws_size,
                              hipStream_t stream) {
  const float* poses = (const float*)d_in[0];
  const float* Wih   = (const float*)d_in[1];
  const float* Whh   = (const float*)d_in[2];
  const float* Wfc   = (const float*)d_in[3];
  const float* bfc   = (const float*)d_in[4];
  if (ws_size < (size_t)(BAR_OFF + BAR_BYTES)) return;

  char* ws = (char*)d_ws;
  bf16* Wcat = (bf16*)(ws + WCAT_OFF);
  bf16* Wfcb = (bf16*)(ws + WFC_OFF);
  bf16* X    = (bf16*)(ws + X_OFF);
  bf16* H    = (bf16*)(ws + H_OFF);
  int*  bar  = (int*)(ws + BAR_OFF);
  float* out = (float*)d_out;

  // zero h ping-pong + barrier slots (contiguous region)
  k_zero<<<256, 256, 0, stream>>>((uint32_t*)(ws + H_OFF), (int)((H_BYTES + BAR_BYTES) / 4));
  // zero decoder X slots 120..142 (incl. pad cols)
  k_zero<<<256, 256, 0, stream>>>((uint32_t*)(X + (size_t)120 * NB * NPPAD),
                                  (int)(23l * NB * NPPAD * 2 / 4));
  k_wcat<<<4096, 256, 0, stream>>>(Whh, Wih, Wcat);
  k_wfc<<<144, 256, 0, stream>>>(Wfc, Wfcb);
  k_x<<<120 * 256, 256, 0, stream>>>(poses, X);
  k_main<<<NWG, 256, 0, stream>>>(poses, bfc, Wcat, Wfcb, X, H, bar, (float*)d_out);
}

// Round 2
// 5619.185 us; speedup vs baseline: 1.1451x; 1.1451x over previous
//
#include <hip/hip_runtime.h>
#include <stdint.h>

#define NB 256          // batch
#define NH 1024         // hidden
#define NPOSE 135
#define NPPAD 160       // pose padded to 160 (mult of 32)
#define NSTEPS 143      // 119 encoder + 24 decoder cell steps
#define NDEC 24
#define KTOT 1184       // 1024 (h) + 160 (x padded)
#define LSTR 168        // LDS row stride in elems (pad breaks bank pattern)
#define NWG 256

typedef __bf16 bf16;
typedef __attribute__((ext_vector_type(8))) __bf16 bf16x8;
typedef __attribute__((ext_vector_type(4))) float f32x4;

// ---- ws layout (bytes), all 256-aligned ----
#define WCAT_OFF 0
#define WCAT_BYTES (4096l * KTOT * 2)              // 9,699,328
#define WFC_OFF  (WCAT_OFF + WCAT_BYTES)
#define WFC_BYTES (144l * 1024 * 2)                // 294,912
#define X_OFF    (WFC_OFF + WFC_BYTES)
#define X_BYTES  (143l * NB * NPPAD * 2)           // 11,714,560
#define H_OFF    (X_OFF + X_BYTES)
#define H_BYTES  (2l * NB * NH * 2)                // ping-pong h, 1,048,576
#define BAR_OFF  (H_OFF + H_BYTES)
#define BAR_BYTES 16384
// bar layout (ints, 32-int = 128B line granularity):
//   arr[g]  at bar[g*32],        g=0..31   (8 WGs per group, monotonic counts)
//   root    at bar[32*32]
//   rel[g]  at bar[(33+g)*32]    (read-only poll lines, one per group)

__global__ void k_zero(uint32_t* p, int n) {
  int i = blockIdx.x * blockDim.x + threadIdx.x;
  int st = gridDim.x * blockDim.x;
  for (; i < n; i += st) p[i] = 0u;
}

// W_cat[n][k] bf16: k<1024 -> W_hh[n][k]; 1024<=k<1159 -> W_ih[n][k-1024]; else 0
__global__ void k_wcat(const float* __restrict__ Whh, const float* __restrict__ Wih,
                       bf16* __restrict__ W) {
  int n = blockIdx.x;
  for (int kk = threadIdx.x; kk < KTOT; kk += blockDim.x) {
    float v = 0.f;
    if (kk < NH) v = Whh[(size_t)n * NH + kk];
    else if (kk - NH < NPOSE) v = Wih[(size_t)n * NPOSE + (kk - NH)];
    W[(size_t)n * KTOT + kk] = (bf16)v;
  }
}

// Wfcb[p][k] bf16, p padded to 144 rows (zeros)
__global__ void k_wfc(const float* __restrict__ Wfc, bf16* __restrict__ W) {
  int p = blockIdx.x;
  for (int kk = threadIdx.x; kk < NH; kk += blockDim.x) {
    float v = (p < NPOSE) ? Wfc[(size_t)p * NH + kk] : 0.f;
    W[(size_t)p * NH + kk] = (bf16)v;
  }
}

// X[t][b][p] bf16 for t=0..119 (encoder inputs + inp0), pad p>=135 with 0
__global__ void k_x(const float* __restrict__ poses, bf16* __restrict__ X) {
  int idx = blockIdx.x;          // t*256 + b, t in [0,120)
  int t = idx >> 8, b = idx & 255;
  int p = threadIdx.x;
  if (p < NPPAD) {
    float v = (p < NPOSE) ? poses[((size_t)b * 144 + t) * NPOSE + p] : 0.f;
    X[(size_t)idx * NPPAD + p] = (bf16)v;
  }
}

__device__ __forceinline__ float sigm(float x) { return 1.f / (1.f + __expf(-x)); }
__device__ __forceinline__ float tanh_(float x) {
  float e = __expf(2.f * x);
  return 1.f - 2.f / (e + 1.f);   // stable for |x| large (inf arithmetic ok)
}

// two-level grid barrier, monotonic phases (no reset), separated poll lines.
// idx = barrier ordinal (0..166); g = L & 31 (8 members per group).
__device__ __forceinline__ void gbar(int* bar, int idx, int g) {
  __syncthreads();
  if (threadIdx.x == 0) {
    __threadfence();                       // release: L2 writeback to LLC (cross-XCD)
    int v = atomicAdd(&bar[g * 32], 1);    // group arrival (8 WGs per line)
    if (v == idx * 8 + 7) {                // last of group -> root
      int r = atomicAdd(&bar[32 * 32], 1);
      if (r == idx * 32 + 31) {            // last group -> broadcast release
        #pragma unroll
        for (int i = 0; i < 32; ++i)
          __hip_atomic_store(&bar[(33 + i) * 32], idx + 1,
                             __ATOMIC_RELAXED, __HIP_MEMORY_SCOPE_AGENT);
      }
    }
    while (__hip_atomic_load(&bar[(33 + g) * 32],
                             __ATOMIC_RELAXED, __HIP_MEMORY_SCOPE_AGENT) <= idx)
      __builtin_amdgcn_s_sleep(2);
    __threadfence();                       // acquire: invalidate stale L1/L2
  }
  __syncthreads();
}

__global__ __launch_bounds__(256) void
k_main(const float* __restrict__ poses, const float* __restrict__ bfc,
       const bf16* __restrict__ Wcat, const bf16* __restrict__ Wfcb,
       bf16* __restrict__ X, bf16* __restrict__ H, int* __restrict__ bar,
       float* __restrict__ out) {
  __shared__ bf16 Alds[64 * LSTR];
  __shared__ bf16 Blds[64 * LSTR];
  const int tid  = threadIdx.x;
  const int lane = tid & 63;
  const int wv   = tid >> 6;        // wave 0..3 -> 16-row b slice
  const int cl   = lane & 15;       // frag row (A/B) and output col (C)
  const int quad = lane >> 4;       // k-subblock / output row group
  const int L    = blockIdx.x;
  const int g    = L & 31;          // barrier arrival group
  // XCD-aware mapping: each XCD owns 8 consecutive j-blocks (W L2 residency)
  const int jb = (L & 7) * 8 + ((L >> 3) & 7);   // 0..63
  const int bb = L >> 6;                          // 0..3
  const int b0 = bb * 64;
  const int j0 = jb * 16;

  float cst[4] = {0.f, 0.f, 0.f, 0.f};  // c-state lives in registers all 143 steps
  int slot = 0;

  for (int s = 0; s < NSTEPS; ++s) {
    bf16* Hr = H + (size_t)(s & 1) * (NB * NH);        // read h(s)
    bf16* Hw = H + (size_t)((s + 1) & 1) * (NB * NH);  // write h(s+1)
    f32x4 acc0 = {0,0,0,0}, acc1 = {0,0,0,0}, acc2 = {0,0,0,0}, acc3 = {0,0,0,0};

    for (int ch = 0; ch < 9; ++ch) {
      // ---- stage A (64b x w) and B (64cols x w) into LDS ----
      if (ch < 8) {   // w = 128, from Hr
        const bf16* ga = Hr + (size_t)b0 * NH + ch * 128;
        for (int u = tid; u < 64 * 16; u += 256) {
          int r = u >> 4, iu = u & 15;
          *(bf16x8*)&Alds[r * LSTR + iu * 8] = *(const bf16x8*)&ga[(size_t)r * NH + iu * 8];
        }
        for (int u = tid; u < 64 * 16; u += 256) {
          int r = u >> 4, iu = u & 15;
          int n = (r >> 4) * NH + j0 + (r & 15);       // gate-major col -> W row
          *(bf16x8*)&Blds[r * LSTR + iu * 8] =
              *(const bf16x8*)&Wcat[(size_t)n * KTOT + ch * 128 + iu * 8];
        }
      } else {        // w = 160, from X[s]
        const bf16* ga = X + ((size_t)s * NB + b0) * NPPAD;
        for (int u = tid; u < 64 * 20; u += 256) {
          int r = u / 20, iu = u % 20;
          *(bf16x8*)&Alds[r * LSTR + iu * 8] = *(const bf16x8*)&ga[(size_t)r * NPPAD + iu * 8];
        }
        for (int u = tid; u < 64 * 20; u += 256) {
          int r = u / 20, iu = u % 20;
          int n = (r >> 4) * NH + j0 + (r & 15);
          *(bf16x8*)&Blds[r * LSTR + iu * 8] =
              *(const bf16x8*)&Wcat[(size_t)n * KTOT + NH + iu * 8];
        }
      }
      __syncthreads();
      const int nks = (ch < 8) ? 4 : 5;
      for (int ks = 0; ks < nks; ++ks) {
        bf16x8 af  = *(const bf16x8*)&Alds[(wv * 16 + cl) * LSTR + ks * 32 + quad * 8];
        bf16x8 bf0 = *(const bf16x8*)&Blds[( 0 + cl) * LSTR + ks * 32 + quad * 8];
        bf16x8 bf1 = *(const bf16x8*)&Blds[(16 + cl) * LSTR + ks * 32 + quad * 8];
        bf16x8 bf2 = *(const bf16x8*)&Blds[(32 + cl) * LSTR + ks * 32 + quad * 8];
        bf16x8 bf3 = *(const bf16x8*)&Blds[(48 + cl) * LSTR + ks * 32 + quad * 8];
        acc0 = __builtin_amdgcn_mfma_f32_16x16x32_bf16(af, bf0, acc0, 0, 0, 0);
        acc1 = __builtin_amdgcn_mfma_f32_16x16x32_bf16(af, bf1, acc1, 0, 0, 0);
        acc2 = __builtin_amdgcn_mfma_f32_16x16x32_bf16(af, bf2, acc2, 0, 0, 0);
        acc3 = __builtin_amdgcn_mfma_f32_16x16x32_bf16(af, bf3, acc3, 0, 0, 0);
      }
      __syncthreads();
    }

    // ---- activations + state update; each lane owns (b, j) for r=0..3 ----
    #pragma unroll
    for (int r = 0; r < 4; ++r) {
      float gi = sigm(acc0[r]);
      float gf = sigm(acc1[r]);
      float gg = tanh_(acc2[r]);
      float go = sigm(acc3[r]);
      float cn = gf * cst[r] + gi * gg;
      cst[r] = cn;
      float h = go * tanh_(cn);
      Hw[(size_t)(b0 + wv * 16 + quad * 4 + r) * NH + j0 + cl] = (bf16)h;
    }
    gbar(bar, slot++, g);

    if (s >= 119) {   // decoder: out = inp + h_new @ W_fc^T + b_fc
      const int k = s - 119;
      if (L < 16) {   // WG L handles batch rows 16L..16L+15
        f32x4 oa[3] = {{0,0,0,0},{0,0,0,0},{0,0,0,0}};
        const bf16* hrow = Hw + (size_t)(L * 16 + cl) * NH;
        for (int ks = 0; ks < 32; ++ks) {
          bf16x8 af = *(const bf16x8*)&hrow[ks * 32 + quad * 8];
          #pragma unroll
          for (int i = 0; i < 3; ++i) {
            int ct = wv + i * 4;           // wave wv covers col-tiles wv, wv+4, wv+8
            if (ct > 8) continue;
            bf16x8 bw = *(const bf16x8*)&Wfcb[(size_t)(ct * 16 + cl) * NH + ks * 32 + quad * 8];
            oa[i] = __builtin_amdgcn_mfma_f32_16x16x32_bf16(af, bw, oa[i], 0, 0, 0);
          }
        }
        #pragma unroll
        for (int i = 0; i < 3; ++i) {
          int ct = wv + i * 4;
          if (ct > 8) continue;
          int p = ct * 16 + cl;
          if (p < NPOSE) {
            #pragma unroll
            for (int r = 0; r < 4; ++r) {
              int b = L * 16 + quad * 4 + r;
              float inp = (k == 0) ? poses[((size_t)b * 144 + 119) * NPOSE + p]
                                   : out[((size_t)b * NDEC + (k - 1)) * NPOSE + p];
              float v = oa[i][r] + inp + bfc[p];     // additive chain kept fp32
              out[((size_t)b * NDEC + k) * NPOSE + p] = v;
              if (s + 1 < NSTEPS)
                X[((size_t)(s + 1) * NB + b) * NPPAD + p] = (bf16)v;
            }
          }
        }
      }
      gbar(bar, slot++, g);
    }
  }
}

extern "C" void kernel_launch(void* const* d_in, const int* in_sizes, int n_in,
                              void* d_out, int out_size, void* d_ws, size_t ws_size,
                              hipStream_t stream) {
  const float* poses = (const float*)d_in[0];
  const float* Wih   = (const float*)d_in[1];
  const float* Whh   = (const float*)d_in[2];
  const float* Wfc   = (const float*)d_in[3];
  const float* bfc   = (const float*)d_in[4];
  if (ws_size < (size_t)(BAR_OFF + BAR_BYTES)) return;

  char* ws = (char*)d_ws;
  bf16* Wcat = (bf16*)(ws + WCAT_OFF);
  bf16* Wfcb = (bf16*)(ws + WFC_OFF);
  bf16* X    = (bf16*)(ws + X_OFF);
  bf16* H    = (bf16*)(ws + H_OFF);
  int*  bar  = (int*)(ws + BAR_OFF);
  float* out = (float*)d_out;

  // zero h ping-pong + barrier area (contiguous region)
  k_zero<<<256, 256, 0, stream>>>((uint32_t*)(ws + H_OFF), (int)((H_BYTES + BAR_BYTES) / 4));
  // zero decoder X slots 120..142 (incl. pad cols)
  k_zero<<<256, 256, 0, stream>>>((uint32_t*)(X + (size_t)120 * NB * NPPAD),
                                  (int)(23l * NB * NPPAD * 2 / 4));
  k_wcat<<<4096, 256, 0, stream>>>(Whh, Wih, Wcat);
  k_wfc<<<144, 256, 0, stream>>>(Wfc, Wfcb);
  k_x<<<120 * 256, 256, 0, stream>>>(poses, X);
  k_main<<<NWG, 256, 0, stream>>>(poses, bfc, Wcat, Wfcb, X, H, bar, (float*)d_out);
}

// Round 3
// 2983.896 us; speedup vs baseline: 2.1565x; 1.8832x over previous
//
#include <hip/hip_runtime.h>
#include <stdint.h>

#define NB 256          // batch
#define NH 1024         // hidden
#define NPOSE 135
#define NPPAD 160       // pose padded to 160 (mult of 32)
#define NSTEPS 143      // 119 encoder + 24 decoder cell steps
#define NDEC 24
#define KTOT 1184       // 1024 (h) + 160 (x padded)
#define LSTR 168        // LDS row stride in elems (pad breaks bank pattern)
#define NWG 256

typedef __bf16 bf16;
typedef __attribute__((ext_vector_type(8))) __bf16 bf16x8;
typedef __attribute__((ext_vector_type(4))) float f32x4;
typedef __attribute__((ext_vector_type(4))) uint32_t u32x4;

// ---- ws layout (bytes), all 256-aligned ----
#define WCAT_OFF 0
#define WCAT_BYTES (4096l * KTOT * 2)              // 9,699,328
#define WFC_OFF  (WCAT_OFF + WCAT_BYTES)
#define WFC_BYTES (144l * 1024 * 2)                // 294,912
#define X_OFF    (WFC_OFF + WFC_BYTES)
#define X_BYTES  (143l * NB * NPPAD * 2)           // 11,714,560
#define H_OFF    (X_OFF + X_BYTES)
#define H_BYTES  (2l * NB * NH * 2)                // ping-pong h, 1,048,576
#define BAR_OFF  (H_OFF + H_BYTES)
#define BAR_BYTES 16384
// bar layout (ints, 32-int = 128B line granularity):
//   arr[g]  at bar[g*32],        g=0..31   (8 WGs per group, monotonic counts)
//   root    at bar[32*32]
//   rel[g]  at bar[(33+g)*32]    (read-only poll lines, one per group)

// ---- LLC-coherent (L1/L2-bypass) access helpers: cross-XCD data WITHOUT fences ----
__device__ __forceinline__ u32x4 llc_ld16(const void* p) {
  u32x4 v;
  asm volatile("global_load_dwordx4 %0, %1, off sc0 sc1"
               : "=v"(v) : "v"(p) : "memory");
  return v;
}
__device__ __forceinline__ void llc_st2(void* p, uint32_t v) {
  asm volatile("global_store_short %0, %1, off sc0 sc1"
               :: "v"(p), "v"(v) : "memory");
}
__device__ __forceinline__ void vm_drain() {
  asm volatile("s_waitcnt vmcnt(0)" ::: "memory");
  __builtin_amdgcn_sched_barrier(0);     // rule #18: pin consumers after the wait
}

__global__ void k_zero(uint32_t* p, int n) {
  int i = blockIdx.x * blockDim.x + threadIdx.x;
  int st = gridDim.x * blockDim.x;
  for (; i < n; i += st) p[i] = 0u;
}

// W_cat[n][k] bf16: k<1024 -> W_hh[n][k]; 1024<=k<1159 -> W_ih[n][k-1024]; else 0
__global__ void k_wcat(const float* __restrict__ Whh, const float* __restrict__ Wih,
                       bf16* __restrict__ W) {
  int n = blockIdx.x;
  for (int kk = threadIdx.x; kk < KTOT; kk += blockDim.x) {
    float v = 0.f;
    if (kk < NH) v = Whh[(size_t)n * NH + kk];
    else if (kk - NH < NPOSE) v = Wih[(size_t)n * NPOSE + (kk - NH)];
    W[(size_t)n * KTOT + kk] = (bf16)v;
  }
}

// Wfcb[p][k] bf16, p padded to 144 rows (zeros)
__global__ void k_wfc(const float* __restrict__ Wfc, bf16* __restrict__ W) {
  int p = blockIdx.x;
  for (int kk = threadIdx.x; kk < NH; kk += blockDim.x) {
    float v = (p < NPOSE) ? Wfc[(size_t)p * NH + kk] : 0.f;
    W[(size_t)p * NH + kk] = (bf16)v;
  }
}

// X[t][b][p] bf16 for t=0..119 (encoder inputs + inp0), pad p>=135 with 0
__global__ void k_x(const float* __restrict__ poses, bf16* __restrict__ X) {
  int idx = blockIdx.x;          // t*256 + b, t in [0,120)
  int t = idx >> 8, b = idx & 255;
  int p = threadIdx.x;
  if (p < NPPAD) {
    float v = (p < NPOSE) ? poses[((size_t)b * 144 + t) * NPOSE + p] : 0.f;
    X[(size_t)idx * NPPAD + p] = (bf16)v;
  }
}

__device__ __forceinline__ float sigm(float x) { return 1.f / (1.f + __expf(-x)); }
__device__ __forceinline__ float tanh_(float x) {
  float e = __expf(2.f * x);
  return 1.f - 2.f / (e + 1.f);   // stable for |x| large (inf arithmetic ok)
}

// two-level grid barrier, monotonic phases, NO cache fences (all cross-XCD data
// moves via llc_* bypass ops; vmcnt(0) before arrival makes them LLC-visible).
__device__ __forceinline__ void gbar(int* bar, int idx, int g) {
  asm volatile("s_waitcnt vmcnt(0)" ::: "memory");   // own bypass stores acked
  __syncthreads();
  if (threadIdx.x == 0) {
    int v = atomicAdd(&bar[g * 32], 1);    // group arrival (8 WGs per line)
    if (v == idx * 8 + 7) {                // last of group -> root
      int r = atomicAdd(&bar[32 * 32], 1);
      if (r == idx * 32 + 31) {            // last group -> broadcast release
        #pragma unroll
        for (int i = 0; i < 32; ++i)
          __hip_atomic_store(&bar[(33 + i) * 32], idx + 1,
                             __ATOMIC_RELAXED, __HIP_MEMORY_SCOPE_AGENT);
      }
    }
    while (__hip_atomic_load(&bar[(33 + g) * 32],
                             __ATOMIC_RELAXED, __HIP_MEMORY_SCOPE_AGENT) <= idx)
      __builtin_amdgcn_s_sleep(2);
  }
  __syncthreads();
}

__global__ __launch_bounds__(256) void
k_main(const float* __restrict__ poses, const float* __restrict__ bfc,
       const bf16* __restrict__ Wcat, const bf16* __restrict__ Wfcb,
       bf16* __restrict__ X, bf16* __restrict__ H, int* __restrict__ bar,
       float* __restrict__ out) {
  __shared__ bf16 Alds[64 * LSTR];
  __shared__ bf16 Blds[64 * LSTR];
  const int tid  = threadIdx.x;
  const int lane = tid & 63;
  const int wv   = tid >> 6;        // wave 0..3 -> 16-row b slice
  const int cl   = lane & 15;       // frag row (A/B) and output col (C)
  const int quad = lane >> 4;       // k-subblock / output row group
  const int L    = blockIdx.x;
  const int g    = L & 31;          // barrier arrival group
  // XCD-aware mapping: each XCD owns 8 consecutive j-blocks (W L2 residency)
  const int jb = (L & 7) * 8 + ((L >> 3) & 7);   // 0..63
  const int bb = L >> 6;                          // 0..3
  const int b0 = bb * 64;
  const int j0 = jb * 16;

  float cst[4] = {0.f, 0.f, 0.f, 0.f};  // c-state lives in registers all 143 steps
  int slot = 0;

  for (int s = 0; s < NSTEPS; ++s) {
    bf16* Hr = H + (size_t)(s & 1) * (NB * NH);        // read h(s)
    bf16* Hw = H + (size_t)((s + 1) & 1) * (NB * NH);  // write h(s+1)
    f32x4 acc0 = {0,0,0,0}, acc1 = {0,0,0,0}, acc2 = {0,0,0,0}, acc3 = {0,0,0,0};

    for (int ch = 0; ch < 9; ++ch) {
      // ---- stage A (64b x w) and B (64cols x w) into LDS ----
      if (ch < 8) {   // w = 128; A from Hr via LLC-bypass (cross-XCD data)
        const bf16* ga = Hr + (size_t)b0 * NH + ch * 128;
        u32x4 av[4];
        #pragma unroll
        for (int it = 0; it < 4; ++it) {
          int u = tid + it * 256;
          int r = u >> 4, iu = u & 15;
          av[it] = llc_ld16(&ga[(size_t)r * NH + iu * 8]);
        }
        // B from Wcat: regular cached loads (read-only, stays L2-resident)
        for (int u = tid; u < 64 * 16; u += 256) {
          int r = u >> 4, iu = u & 15;
          int n = (r >> 4) * NH + j0 + (r & 15);       // gate-major col -> W row
          *(bf16x8*)&Blds[r * LSTR + iu * 8] =
              *(const bf16x8*)&Wcat[(size_t)n * KTOT + ch * 128 + iu * 8];
        }
        vm_drain();
        #pragma unroll
        for (int it = 0; it < 4; ++it) {
          int u = tid + it * 256;
          int r = u >> 4, iu = u & 15;
          *(u32x4*)&Alds[r * LSTR + iu * 8] = av[it];
        }
      } else {        // w = 160, A from X[s]
        const bf16* ga = X + ((size_t)s * NB + b0) * NPPAD;
        if (s < 120) {       // encoder X: read-only prestaged, cached loads
          for (int u = tid; u < 64 * 20; u += 256) {
            int r = u / 20, iu = u % 20;
            *(bf16x8*)&Alds[r * LSTR + iu * 8] = *(const bf16x8*)&ga[(size_t)r * NPPAD + iu * 8];
          }
          for (int u = tid; u < 64 * 20; u += 256) {
            int r = u / 20, iu = u % 20;
            int n = (r >> 4) * NH + j0 + (r & 15);
            *(bf16x8*)&Blds[r * LSTR + iu * 8] =
                *(const bf16x8*)&Wcat[(size_t)n * KTOT + NH + iu * 8];
          }
        } else {             // decoder X: written cross-XCD each step -> bypass
          u32x4 av[5];
          #pragma unroll
          for (int it = 0; it < 5; ++it) {
            int u = tid + it * 256;
            int r = u / 20, iu = u % 20;
            av[it] = llc_ld16(&ga[(size_t)r * NPPAD + iu * 8]);
          }
          for (int u = tid; u < 64 * 20; u += 256) {
            int r = u / 20, iu = u % 20;
            int n = (r >> 4) * NH + j0 + (r & 15);
            *(bf16x8*)&Blds[r * LSTR + iu * 8] =
                *(const bf16x8*)&Wcat[(size_t)n * KTOT + NH + iu * 8];
          }
          vm_drain();
          #pragma unroll
          for (int it = 0; it < 5; ++it) {
            int u = tid + it * 256;
            int r = u / 20, iu = u % 20;
            *(u32x4*)&Alds[r * LSTR + iu * 8] = av[it];
          }
        }
      }
      __syncthreads();
      const int nks = (ch < 8) ? 4 : 5;
      for (int ks = 0; ks < nks; ++ks) {
        bf16x8 af  = *(const bf16x8*)&Alds[(wv * 16 + cl) * LSTR + ks * 32 + quad * 8];
        bf16x8 bf0 = *(const bf16x8*)&Blds[( 0 + cl) * LSTR + ks * 32 + quad * 8];
        bf16x8 bf1 = *(const bf16x8*)&Blds[(16 + cl) * LSTR + ks * 32 + quad * 8];
        bf16x8 bf2 = *(const bf16x8*)&Blds[(32 + cl) * LSTR + ks * 32 + quad * 8];
        bf16x8 bf3 = *(const bf16x8*)&Blds[(48 + cl) * LSTR + ks * 32 + quad * 8];
        acc0 = __builtin_amdgcn_mfma_f32_16x16x32_bf16(af, bf0, acc0, 0, 0, 0);
        acc1 = __builtin_amdgcn_mfma_f32_16x16x32_bf16(af, bf1, acc1, 0, 0, 0);
        acc2 = __builtin_amdgcn_mfma_f32_16x16x32_bf16(af, bf2, acc2, 0, 0, 0);
        acc3 = __builtin_amdgcn_mfma_f32_16x16x32_bf16(af, bf3, acc3, 0, 0, 0);
      }
      __syncthreads();
    }

    // ---- activations + state update; each lane owns (b, j) for r=0..3 ----
    #pragma unroll
    for (int r = 0; r < 4; ++r) {
      float gi = sigm(acc0[r]);
      float gf = sigm(acc1[r]);
      float gg = tanh_(acc2[r]);
      float go = sigm(acc3[r]);
      float cn = gf * cst[r] + gi * gg;
      cst[r] = cn;
      float h = go * tanh_(cn);
      bf16 hb = (bf16)h;
      uint32_t hv = (uint32_t)__builtin_bit_cast(uint16_t, hb);
      llc_st2(&Hw[(size_t)(b0 + wv * 16 + quad * 4 + r) * NH + j0 + cl], hv);
    }
    gbar(bar, slot++, g);

    if (s >= 119) {   // decoder: out = inp + h_new @ W_fc^T + b_fc
      const int k = s - 119;
      if (L < 16) {   // WG L handles batch rows 16L..16L+15
        f32x4 oa[3] = {{0,0,0,0},{0,0,0,0},{0,0,0,0}};
        const bf16* hrow = Hw + (size_t)(L * 16 + cl) * NH;
        for (int kb = 0; kb < 4; ++kb) {   // h written cross-XCD -> bypass loads
          u32x4 hv[8];
          #pragma unroll
          for (int t = 0; t < 8; ++t)
            hv[t] = llc_ld16(&hrow[(kb * 8 + t) * 32 + quad * 8]);
          vm_drain();
          #pragma unroll
          for (int t = 0; t < 8; ++t) {
            bf16x8 af = __builtin_bit_cast(bf16x8, hv[t]);
            #pragma unroll
            for (int i = 0; i < 3; ++i) {
              int ct = wv + i * 4;         // wave wv covers col-tiles wv, wv+4, wv+8
              if (ct > 8) continue;
              bf16x8 bw = *(const bf16x8*)&Wfcb[(size_t)(ct * 16 + cl) * NH
                                                + (kb * 8 + t) * 32 + quad * 8];
              oa[i] = __builtin_amdgcn_mfma_f32_16x16x32_bf16(af, bw, oa[i], 0, 0, 0);
            }
          }
        }
        #pragma unroll
        for (int i = 0; i < 3; ++i) {
          int ct = wv + i * 4;
          if (ct > 8) continue;
          int p = ct * 16 + cl;
          if (p < NPOSE) {
            #pragma unroll
            for (int r = 0; r < 4; ++r) {
              int b = L * 16 + quad * 4 + r;
              float inp = (k == 0) ? poses[((size_t)b * 144 + 119) * NPOSE + p]
                                   : out[((size_t)b * NDEC + (k - 1)) * NPOSE + p];
              float v = oa[i][r] + inp + bfc[p];     // additive chain kept fp32
              out[((size_t)b * NDEC + k) * NPOSE + p] = v;   // same-lane RAW next step
              if (s + 1 < NSTEPS) {
                bf16 xb = (bf16)v;
                llc_st2(&X[((size_t)(s + 1) * NB + b) * NPPAD + p],
                        (uint32_t)__builtin_bit_cast(uint16_t, xb));
              }
            }
          }
        }
      }
      gbar(bar, slot++, g);
    }
  }
}

extern "C" void kernel_launch(void* const* d_in, const int* in_sizes, int n_in,
                              void* d_out, int out_size, void* d_ws, size_t ws_size,
                              hipStream_t stream) {
  const float* poses = (const float*)d_in[0];
  const float* Wih   = (const float*)d_in[1];
  const float* Whh   = (const float*)d_in[2];
  const float* Wfc   = (const float*)d_in[3];
  const float* bfc   = (const float*)d_in[4];
  if (ws_size < (size_t)(BAR_OFF + BAR_BYTES)) return;

  char* ws = (char*)d_ws;
  bf16* Wcat = (bf16*)(ws + WCAT_OFF);
  bf16* Wfcb = (bf16*)(ws + WFC_OFF);
  bf16* X    = (bf16*)(ws + X_OFF);
  bf16* H    = (bf16*)(ws + H_OFF);
  int*  bar  = (int*)(ws + BAR_OFF);
  float* out = (float*)d_out;

  // zero h ping-pong + barrier area (contiguous region)
  k_zero<<<256, 256, 0, stream>>>((uint32_t*)(ws + H_OFF), (int)((H_BYTES + BAR_BYTES) / 4));
  // zero decoder X slots 120..142 (incl. pad cols)
  k_zero<<<256, 256, 0, stream>>>((uint32_t*)(X + (size_t)120 * NB * NPPAD),
                                  (int)(23l * NB * NPPAD * 2 / 4));
  k_wcat<<<4096, 256, 0, stream>>>(Whh, Wih, Wcat);
  k_wfc<<<144, 256, 0, stream>>>(Wfc, Wfcb);
  k_x<<<120 * 256, 256, 0, stream>>>(poses, X);
  k_main<<<NWG, 256, 0, stream>>>(poses, bfc, Wcat, Wfcb, X, H, bar, (float*)d_out);
}

// Round 4
// 2081.135 us; speedup vs baseline: 3.0919x; 1.4338x over previous
//
#include <hip/hip_runtime.h>
#include <stdint.h>

#define NB 256          // batch
#define NH 1024         // hidden
#define NPOSE 135
#define NPPAD 160       // pose padded to 160 (mult of 32)
#define NSTEPS 143      // 119 encoder + 24 decoder cell steps
#define NDEC 24
#define KTOT 1184       // 1024 (h) + 160 (x padded)
#define LSTR 168        // LDS row stride in elems
#define NWG 256

typedef __bf16 bf16;
typedef __attribute__((ext_vector_type(8))) __bf16 bf16x8;
typedef __attribute__((ext_vector_type(4))) float f32x4;
typedef __attribute__((ext_vector_type(4))) uint32_t u32x4;

// ---- ws layout (bytes) ----
#define WCAT_OFF 0
#define WCAT_BYTES (4096l * KTOT * 2)
#define WFC_OFF  (WCAT_OFF + WCAT_BYTES)
#define WFC_BYTES (144l * 1024 * 2)
#define X_OFF    (WFC_OFF + WFC_BYTES)
#define X_BYTES  (143l * NB * NPPAD * 2)
#define H_OFF    (X_OFF + X_BYTES)
#define H_BYTES  (2l * NB * NH * 2)
#define BAR_OFF  (H_OFF + H_BYTES)
#define BAR_BYTES 16384

// ---- LLC-coherent (L1/L2-bypass) ops: cross-XCD data WITHOUT fences ----
__device__ __forceinline__ u32x4 llc_ld16(const void* p) {
  u32x4 v;
  asm volatile("global_load_dwordx4 %0, %1, off sc0 sc1"
               : "=v"(v) : "v"(p) : "memory");
  return v;
}
__device__ __forceinline__ u32x4 g_ld16(const void* p) {   // cached (L2-resident W/X)
  u32x4 v;
  asm volatile("global_load_dwordx4 %0, %1, off"
               : "=v"(v) : "v"(p) : "memory");
  return v;
}
__device__ __forceinline__ void llc_st2(void* p, uint32_t v) {
  asm volatile("global_store_short %0, %1, off sc0 sc1"
               :: "v"(p), "v"(v) : "memory");
}
__device__ __forceinline__ void vm_drain() {
  asm volatile("s_waitcnt vmcnt(0)" ::: "memory");
  __builtin_amdgcn_sched_barrier(0);     // rule #18: pin consumers after the wait
}

__global__ void k_zero(uint32_t* p, int n) {
  int i = blockIdx.x * blockDim.x + threadIdx.x;
  int st = gridDim.x * blockDim.x;
  for (; i < n; i += st) p[i] = 0u;
}

__global__ void k_wcat(const float* __restrict__ Whh, const float* __restrict__ Wih,
                       bf16* __restrict__ W) {
  int n = blockIdx.x;
  for (int kk = threadIdx.x; kk < KTOT; kk += blockDim.x) {
    float v = 0.f;
    if (kk < NH) v = Whh[(size_t)n * NH + kk];
    else if (kk - NH < NPOSE) v = Wih[(size_t)n * NPOSE + (kk - NH)];
    W[(size_t)n * KTOT + kk] = (bf16)v;
  }
}

__global__ void k_wfc(const float* __restrict__ Wfc, bf16* __restrict__ W) {
  int p = blockIdx.x;
  for (int kk = threadIdx.x; kk < NH; kk += blockDim.x) {
    float v = (p < NPOSE) ? Wfc[(size_t)p * NH + kk] : 0.f;
    W[(size_t)p * NH + kk] = (bf16)v;
  }
}

__global__ void k_x(const float* __restrict__ poses, bf16* __restrict__ X) {
  int idx = blockIdx.x;          // t*256 + b, t in [0,120)
  int t = idx >> 8, b = idx & 255;
  int p = threadIdx.x;
  if (p < NPPAD) {
    float v = (p < NPOSE) ? poses[((size_t)b * 144 + t) * NPOSE + p] : 0.f;
    X[(size_t)idx * NPPAD + p] = (bf16)v;
  }
}

__device__ __forceinline__ float sigm(float x) { return 1.f / (1.f + __expf(-x)); }
__device__ __forceinline__ float tanh_(float x) {
  float e = __expf(2.f * x);
  return 1.f - 2.f / (e + 1.f);
}

// two-level grid barrier, monotonic phases, no cache fences (bypass data path).
__device__ __forceinline__ void gbar(int* bar, int idx, int g) {
  asm volatile("s_waitcnt vmcnt(0)" ::: "memory");   // own bypass stores acked
  __syncthreads();
  if (threadIdx.x == 0) {
    int v = atomicAdd(&bar[g * 32], 1);
    if (v == idx * 8 + 7) {
      int r = atomicAdd(&bar[32 * 32], 1);
      if (r == idx * 32 + 31) {
        #pragma unroll
        for (int i = 0; i < 32; ++i)
          __hip_atomic_store(&bar[(33 + i) * 32], idx + 1,
                             __ATOMIC_RELAXED, __HIP_MEMORY_SCOPE_AGENT);
      }
    }
    while (__hip_atomic_load(&bar[(33 + g) * 32],
                             __ATOMIC_RELAXED, __HIP_MEMORY_SCOPE_AGENT) <= idx)
      __builtin_amdgcn_s_sleep(2);
  }
  __syncthreads();
}

__global__ __launch_bounds__(256) void
k_main(const float* __restrict__ poses, const float* __restrict__ bfc,
       const bf16* __restrict__ Wcat, const bf16* __restrict__ Wfcb,
       bf16* __restrict__ X, bf16* __restrict__ H, int* __restrict__ bar,
       float* __restrict__ out) {
  __shared__ bf16 Alds[2 * 64 * LSTR];     // double-buffered
  __shared__ bf16 Blds[2 * 64 * LSTR];
  const int tid  = threadIdx.x;
  const int lane = tid & 63;
  const int wv   = tid >> 6;
  const int cl   = lane & 15;
  const int quad = lane >> 4;
  const int L    = blockIdx.x;
  const int g    = L & 31;
  const int jb = (L & 7) * 8 + ((L >> 3) & 7);   // XCD-aware j-block
  const int bb = L >> 6;
  const int b0 = bb * 64;
  const int j0 = jb * 16;

  // ---- precomputed per-thread offsets ----
  const int rA  = tid >> 4;              // 0..15
  const int iu8 = (tid & 15) * 8;
  int offA[4], offB[4], offL[4];
  #pragma unroll
  for (int it = 0; it < 4; ++it) {
    offA[it] = (rA + it * 16) * NH + iu8;                    // into Hr + b0*NH + ch*128
    offB[it] = (it * NH + j0 + rA) * KTOT + iu8;             // into Wcat + ch*128
    offL[it] = (rA + it * 16) * LSTR + iu8;
  }
  int o8x[5], o8w[5], o8l[5];
  #pragma unroll
  for (int it = 0; it < 5; ++it) {
    int u = tid + it * 256, r = u / 20, iu = u % 20;
    o8x[it] = r * NPPAD + iu * 8;                            // into X + (s*NB+b0)*NPPAD
    o8w[it] = ((r >> 4) * NH + j0 + (r & 15)) * KTOT + 1024 + iu * 8;
    o8l[it] = r * LSTR + iu * 8;
  }
  const int aoff = (wv * 16 + cl) * LSTR + quad * 8;
  const int boff = cl * LSTR + quad * 8;

  u32x4 ar[5], br[5];
  float cst[4] = {0.f, 0.f, 0.f, 0.f};
  f32x4 acc0, acc1, acc2, acc3;
  int slot = 0;

  // ---- pipeline helpers ----
  auto issueA_h = [&](const bf16* Hr, int ch) {
    const bf16* ga = Hr + (size_t)b0 * NH + ch * 128;
    #pragma unroll
    for (int it = 0; it < 4; ++it) ar[it] = llc_ld16(ga + offA[it]);
  };
  auto issueB_h = [&](int ch) {
    const bf16* gb = Wcat + ch * 128;
    #pragma unroll
    for (int it = 0; it < 4; ++it) br[it] = g_ld16(gb + offB[it]);
  };
  auto issueA_x = [&](int s) {
    const bf16* ga = X + ((size_t)s * NB + b0) * NPPAD;
    if (s < 120) {                       // static prestaged -> cached
      #pragma unroll
      for (int it = 0; it < 5; ++it) ar[it] = g_ld16(ga + o8x[it]);
    } else {                             // written cross-XCD last step -> bypass
      #pragma unroll
      for (int it = 0; it < 5; ++it) ar[it] = llc_ld16(ga + o8x[it]);
    }
  };
  auto issueB_x = [&]() {
    #pragma unroll
    for (int it = 0; it < 5; ++it) br[it] = g_ld16(Wcat + o8w[it]);
  };
  auto writeL_h = [&](int p) {
    bf16* Al = &Alds[p * 64 * LSTR]; bf16* Bl = &Blds[p * 64 * LSTR];
    #pragma unroll
    for (int it = 0; it < 4; ++it) {
      *(u32x4*)&Al[offL[it]] = ar[it];
      *(u32x4*)&Bl[offL[it]] = br[it];
    }
  };
  auto writeL_x = [&](int p) {
    bf16* Al = &Alds[p * 64 * LSTR]; bf16* Bl = &Blds[p * 64 * LSTR];
    #pragma unroll
    for (int it = 0; it < 5; ++it) {
      *(u32x4*)&Al[o8l[it]] = ar[it];
      *(u32x4*)&Bl[o8l[it]] = br[it];
    }
  };
  auto mfma_phase = [&](int p, int nks) {
    const bf16* Al = &Alds[p * 64 * LSTR];
    const bf16* Bl = &Blds[p * 64 * LSTR];
    #pragma unroll
    for (int ks = 0; ks < 5; ++ks) {
      if (ks == nks) break;
      bf16x8 af  = *(const bf16x8*)&Al[aoff + ks * 32];
      bf16x8 b0f = *(const bf16x8*)&Bl[boff + ks * 32];
      bf16x8 b1f = *(const bf16x8*)&Bl[boff + 16 * LSTR + ks * 32];
      bf16x8 b2f = *(const bf16x8*)&Bl[boff + 32 * LSTR + ks * 32];
      bf16x8 b3f = *(const bf16x8*)&Bl[boff + 48 * LSTR + ks * 32];
      acc0 = __builtin_amdgcn_mfma_f32_16x16x32_bf16(af, b0f, acc0, 0, 0, 0);
      acc1 = __builtin_amdgcn_mfma_f32_16x16x32_bf16(af, b1f, acc1, 0, 0, 0);
      acc2 = __builtin_amdgcn_mfma_f32_16x16x32_bf16(af, b2f, acc2, 0, 0, 0);
      acc3 = __builtin_amdgcn_mfma_f32_16x16x32_bf16(af, b3f, acc3, 0, 0, 0);
    }
  };

  // ---- prologue: prefetch chunk 0 of step 0 ----
  issueB_h(0);
  issueA_h(H, 0);          // h(0) = zeros (k_zero, flushed at dispatch boundary)

  for (int s = 0; s < NSTEPS; ++s) {
    bf16* Hr = H + (size_t)(s & 1) * (NB * NH);
    bf16* Hw = H + (size_t)((s + 1) & 1) * (NB * NH);
    acc0 = f32x4{0,0,0,0}; acc1 = f32x4{0,0,0,0};
    acc2 = f32x4{0,0,0,0}; acc3 = f32x4{0,0,0,0};

    for (int ch = 0; ch < 8; ++ch) {
      vm_drain();                        // loads(ch) arrived
      writeL_h(ch & 1);
      __syncthreads();
      if (ch < 7) { issueB_h(ch + 1); issueA_h(Hr, ch + 1); }   // in flight under MFMA
      else        { issueB_x();        issueA_x(s); }
      mfma_phase(ch & 1, 4);
    }
    vm_drain();                          // chunk 8 (x) arrived
    writeL_x(0);
    __syncthreads();
    mfma_phase(0, 5);

    // ---- activations + h-store (bypass) ----
    #pragma unroll
    for (int r = 0; r < 4; ++r) {
      float gi = sigm(acc0[r]);
      float gf = sigm(acc1[r]);
      float gg = tanh_(acc2[r]);
      float go = sigm(acc3[r]);
      float cn = gf * cst[r] + gi * gg;
      cst[r] = cn;
      float h = go * tanh_(cn);
      bf16 hb = (bf16)h;
      llc_st2(&Hw[(size_t)(b0 + wv * 16 + quad * 4 + r) * NH + j0 + cl],
              (uint32_t)__builtin_bit_cast(uint16_t, hb));
    }
    issueB_h(0);                         // next step's W chunk 0: step-invariant
    gbar(bar, slot++, g);                // drains h-stores; h(s+1) visible

    if (s < 119) {
      issueA_h(Hw, 0);                   // next step reads Hr == this Hw
    } else {
      const int k = s - 119;
      if (L < 16) {                      // out = inp + h_new @ W_fc^T + b_fc
        f32x4 oa[3] = {{0,0,0,0},{0,0,0,0},{0,0,0,0}};
        const bf16* hrow = Hw + (size_t)(L * 16 + cl) * NH;
        for (int kb = 0; kb < 4; ++kb) { // h written cross-XCD -> bypass loads
          u32x4 hv[8];
          #pragma unroll
          for (int t = 0; t < 8; ++t)
            hv[t] = llc_ld16(&hrow[(kb * 8 + t) * 32 + quad * 8]);
          vm_drain();
          #pragma unroll
          for (int t = 0; t < 8; ++t) {
            bf16x8 af = __builtin_bit_cast(bf16x8, hv[t]);
            #pragma unroll
            for (int i = 0; i < 3; ++i) {
              int ct = wv + i * 4;
              if (ct > 8) continue;
              bf16x8 bw = *(const bf16x8*)&Wfcb[(size_t)(ct * 16 + cl) * NH
                                                + (kb * 8 + t) * 32 + quad * 8];
              oa[i] = __builtin_amdgcn_mfma_f32_16x16x32_bf16(af, bw, oa[i], 0, 0, 0);
            }
          }
        }
        #pragma unroll
        for (int i = 0; i < 3; ++i) {
          int ct = wv + i * 4;
          if (ct > 8) continue;
          int p = ct * 16 + cl;
          if (p < NPOSE) {
            #pragma unroll
            for (int r = 0; r < 4; ++r) {
              int b = L * 16 + quad * 4 + r;
              float inp = (k == 0) ? poses[((size_t)b * 144 + 119) * NPOSE + p]
                                   : out[((size_t)b * NDEC + (k - 1)) * NPOSE + p];
              float v = oa[i][r] + inp + bfc[p];     // additive chain kept fp32
              out[((size_t)b * NDEC + k) * NPOSE + p] = v;
              if (s + 1 < NSTEPS) {
                bf16 xb = (bf16)v;
                llc_st2(&X[((size_t)(s + 1) * NB + b) * NPPAD + p],
                        (uint32_t)__builtin_bit_cast(uint16_t, xb));
              }
            }
          }
        }
      }
      gbar(bar, slot++, g);              // X(s+1) visible
      issueA_h(Hw, 0);
    }
  }
}

extern "C" void kernel_launch(void* const* d_in, const int* in_sizes, int n_in,
                              void* d_out, int out_size, void* d_ws, size_t ws_size,
                              hipStream_t stream) {
  const float* poses = (const float*)d_in[0];
  const float* Wih   = (const float*)d_in[1];
  const float* Whh   = (const float*)d_in[2];
  const float* Wfc   = (const float*)d_in[3];
  const float* bfc   = (const float*)d_in[4];
  if (ws_size < (size_t)(BAR_OFF + BAR_BYTES)) return;

  char* ws = (char*)d_ws;
  bf16* Wcat = (bf16*)(ws + WCAT_OFF);
  bf16* Wfcb = (bf16*)(ws + WFC_OFF);
  bf16* X    = (bf16*)(ws + X_OFF);
  bf16* H    = (bf16*)(ws + H_OFF);
  int*  bar  = (int*)(ws + BAR_OFF);

  k_zero<<<256, 256, 0, stream>>>((uint32_t*)(ws + H_OFF), (int)((H_BYTES + BAR_BYTES) / 4));
  k_zero<<<256, 256, 0, stream>>>((uint32_t*)(X + (size_t)120 * NB * NPPAD),
                                  (int)(23l * NB * NPPAD * 2 / 4));
  k_wcat<<<4096, 256, 0, stream>>>(Whh, Wih, Wcat);
  k_wfc<<<144, 256, 0, stream>>>(Wfc, Wfcb);
  k_x<<<120 * 256, 256, 0, stream>>>(poses, X);
  k_main<<<NWG, 256, 0, stream>>>(poses, bfc, Wcat, Wfcb, X, H, bar, (float*)d_out);
}